// Round 1
// baseline (2005.232 us; speedup 1.0000x reference)
//
#include <hip/hip_runtime.h>
#include <hip/hip_bf16.h>
#include <stdint.h>

#define EPSV 1e-5f

typedef __attribute__((ext_vector_type(4)))  int    i32x4;
typedef __attribute__((ext_vector_type(16))) int    i32x16;
typedef __attribute__((ext_vector_type(4)))  float  f32x4;

__device__ __forceinline__ float clampf(float v, float lo, float hi) {
    return fminf(fmaxf(v, lo), hi);
}

__device__ __forceinline__ void gload16(const void* g, void* l) {
    __builtin_amdgcn_global_load_lds(
        (const __attribute__((address_space(1))) void*)g,
        (__attribute__((address_space(3))) void*)l, 16, 0, 0);
}

// ---------------- reduction: sum |w| (double partials, fixed order) ----------
__global__ void k_abs_sum(const float* __restrict__ w, long n4, double* __restrict__ part) {
    const f32x4* w4 = (const f32x4*)w;
    double s = 0.0;
    long stride = (long)gridDim.x * blockDim.x;
    for (long i = (long)blockIdx.x * blockDim.x + threadIdx.x; i < n4; i += stride) {
        f32x4 v = w4[i];
        s += (double)fabsf(v.x) + (double)fabsf(v.y) + (double)fabsf(v.z) + (double)fabsf(v.w);
    }
    for (int m = 1; m < 64; m <<= 1) s += __shfl_xor(s, m, 64);
    __shared__ double ls[4];
    int lane = threadIdx.x & 63, wid = threadIdx.x >> 6;
    if (lane == 0) ls[wid] = s;
    __syncthreads();
    if (threadIdx.x == 0) part[blockIdx.x] = ls[0] + ls[1] + ls[2] + ls[3];
}

__global__ void k_finalize(const double* __restrict__ p1, const double* __restrict__ p2,
                           int np, float* __restrict__ scal, double inv1, double inv2) {
    __shared__ double ls[4];
    for (int which = 0; which < 2; ++which) {
        const double* p = which ? p2 : p1;
        double s = 0.0;
        for (int i = threadIdx.x; i < np; i += 256) s += p[i];
        for (int m = 1; m < 64; m <<= 1) s += __shfl_xor(s, m, 64);
        int lane = threadIdx.x & 63, wid = threadIdx.x >> 6;
        if (lane == 0) ls[wid] = s;
        __syncthreads();
        if (threadIdx.x == 0) {
            double t = ls[0] + ls[1] + ls[2] + ls[3];
            scal[which] = fmaxf((float)(t * (which ? inv2 : inv1)), EPSV);
        }
        __syncthreads();
    }
}

// ---------------- W quantize: ternary {-1,0,1} -------------------------------
__global__ void k_quant_w(const float* __restrict__ w, char* __restrict__ wq,
                          long n4, const float* __restrict__ scal, int which) {
    float ws = scal[which];
    long stride = (long)gridDim.x * blockDim.x;
    for (long i = (long)blockIdx.x * blockDim.x + threadIdx.x; i < n4; i += stride) {
        f32x4 v = ((const f32x4*)w)[i];
        char4 q;
        q.x = (char)(int)clampf(rintf(v.x / ws), -1.f, 1.f);
        q.y = (char)(int)clampf(rintf(v.y / ws), -1.f, 1.f);
        q.z = (char)(int)clampf(rintf(v.z / ws), -1.f, 1.f);
        q.w = (char)(int)clampf(rintf(v.w / ws), -1.f, 1.f);
        ((char4*)wq)[i] = q;
    }
}

// ---------------- x quantize: per-row int8 -----------------------------------
__global__ void k_quant_x(const float* __restrict__ x, char* __restrict__ xq,
                          float* __restrict__ xs1, int K) {
    __shared__ float buf[4096];
    __shared__ float wm[4];
    int row = blockIdx.x;
    const float* xr = x + (size_t)row * K;
    float m = 0.f;
    for (int i = threadIdx.x * 4; i < K; i += 1024) {
        f32x4 v = *(const f32x4*)(xr + i);
        *(f32x4*)&buf[i] = v;
        m = fmaxf(m, fmaxf(fmaxf(fabsf(v.x), fabsf(v.y)), fmaxf(fabsf(v.z), fabsf(v.w))));
    }
    for (int mask = 1; mask < 64; mask <<= 1) m = fmaxf(m, __shfl_xor(m, mask, 64));
    int lane = threadIdx.x & 63, wid = threadIdx.x >> 6;
    if (lane == 0) wm[wid] = m;
    __syncthreads();
    float rm = fmaxf(fmaxf(wm[0], wm[1]), fmaxf(wm[2], wm[3]));
    float sc = 127.f / fmaxf(rm, EPSV);
    if (threadIdx.x == 0) xs1[row] = sc;
    char* xqr = xq + (size_t)row * K;
    for (int i = threadIdx.x * 4; i < K; i += 1024) {
        f32x4 v = *(const f32x4*)&buf[i];
        char4 q;
        q.x = (char)(int)clampf(rintf(v.x * sc), -128.f, 127.f);
        q.y = (char)(int)clampf(rintf(v.y * sc), -128.f, 127.f);
        q.z = (char)(int)clampf(rintf(v.z * sc), -128.f, 127.f);
        q.w = (char)(int)clampf(rintf(v.w * sc), -128.f, 127.f);
        ((char4*)xqr)[i >> 2] = q;
    }
}

// ---------------- per-row layer-2 scales -------------------------------------
__global__ void k_rowscale2(const int* __restrict__ rowmax1, const float* __restrict__ xs1,
                            const float* __restrict__ scal, float* __restrict__ xs2,
                            float* __restrict__ os2, float* __restrict__ g1s,
                            int rowOff, int R) {
    int i = blockIdx.x * 256 + threadIdx.x;
    if (i >= R) return;
    int r = rowOff + i;
    float g1 = scal[0] / xs1[r];                 // w_scale1 / x_scale1
    float rmh = g1 * (float)rowmax1[r];          // max |h| over row (exact, monotone)
    float s2 = 127.f / fmaxf(rmh, EPSV);         // x_scale2
    xs2[r] = s2;
    os2[r] = scal[1] / s2;                       // w_scale2 / x_scale2
    g1s[r] = g1;
}

// ---------------- h requantize: C1 int32 -> int8 ------------------------------
__global__ void k_quant_h(const int* __restrict__ c1, char* __restrict__ xq2,
                          const float* __restrict__ xs2, const float* __restrict__ g1s,
                          int rowOff, long n4) {
    long stride = (long)gridDim.x * blockDim.x;
    for (long i = (long)blockIdx.x * blockDim.x + threadIdx.x; i < n4; i += stride) {
        i32x4 c = ((const i32x4*)c1)[i];
        int r = rowOff + (int)(i >> 12);         // 4096 vec4 per 16384-wide row
        float g1 = g1s[r], s2 = xs2[r];
        char4 q;
        q.x = (char)(int)clampf(rintf(fmaxf((float)c.x, 0.f) * g1 * s2), -128.f, 127.f);
        q.y = (char)(int)clampf(rintf(fmaxf((float)c.y, 0.f) * g1 * s2), -128.f, 127.f);
        q.z = (char)(int)clampf(rintf(fmaxf((float)c.z, 0.f) * g1 * s2), -128.f, 127.f);
        q.w = (char)(int)clampf(rintf(fmaxf((float)c.w, 0.f) * g1 * s2), -128.f, 127.f);
        ((char4*)xq2)[i] = q;
    }
}

// Wait: q must be round(h * s2) with h = fl(C1*g1) — keep op order identical to ref.
// (done above: fmaxf(C1,0)*g1 rounds identically to relu(fl(C1*g1)); then *s2, rintf)

// ---------------- int8 GEMM: C = A[Mx K] * B[N x K]^T ------------------------
// 128x128 tile, BK=64, 4 waves (2x2), mfma_i32_32x32x32_i8, XOR-swizzled LDS.
template<int EPI>
__launch_bounds__(256)
__global__ void k_gemm_i8(const char* __restrict__ A, const char* __restrict__ B,
                          int K, int N,
                          int* __restrict__ C, int* __restrict__ rowmax,
                          float* __restrict__ Out, const float* __restrict__ os2,
                          int rowOff) {
    __shared__ char As[128 * 64];
    __shared__ char Bs[128 * 64];
    const int tid = threadIdx.x;
    const int lane = tid & 63;
    const int wid = tid >> 6;
    const int wr = wid >> 1, wc = wid & 1;
    const size_t Ks = (size_t)K;

    const char* Ab = A + (size_t)blockIdx.y * 128 * Ks;
    const char* Bb = B + (size_t)blockIdx.x * 128 * Ks;

    // staging: linear LDS dest, inverse-swizzled global source (rule #21)
    const int sr = tid >> 2;
    const int sx = ((tid & 3) * 16) ^ (((sr >> 1) & 3) << 4);
    const char* ga  = Ab + (size_t)sr * Ks + sx;
    const char* ga2 = ga + 64 * Ks;
    const char* gb  = Bb + (size_t)sr * Ks + sx;
    const char* gb2 = gb + 64 * Ks;
    char* la  = As + tid * 16;
    char* la2 = la + 4096;
    char* lb  = Bs + tid * 16;
    char* lb2 = lb + 4096;

    const int frow = lane & 31;
    const int fk   = (lane >> 5) * 16;
    const int xr   = ((frow >> 1) & 3) << 4;     // read-side swizzle (same involution)
    const int arow0 = (wr * 64 + frow) * 64;
    const int brow0 = (wc * 64 + frow) * 64;

    i32x16 acc[2][2] = {};

    const int nk = K >> 6;
    for (int kt = 0; kt < nk; ++kt) {
        __syncthreads();
        gload16(ga, la);  gload16(ga2, la2);
        gload16(gb, lb);  gload16(gb2, lb2);
        ga += 64; ga2 += 64; gb += 64; gb2 += 64;
        __syncthreads();
#pragma unroll
        for (int ks = 0; ks < 2; ++ks) {
            const int ko = (ks * 32 + fk) ^ xr;
            i32x4 a0 = *(const i32x4*)(As + arow0 + ko);
            i32x4 a1 = *(const i32x4*)(As + arow0 + 32 * 64 + ko);
            i32x4 b0 = *(const i32x4*)(Bs + brow0 + ko);
            i32x4 b1 = *(const i32x4*)(Bs + brow0 + 32 * 64 + ko);
            acc[0][0] = __builtin_amdgcn_mfma_i32_32x32x32_i8(a0, b0, acc[0][0], 0, 0, 0);
            acc[0][1] = __builtin_amdgcn_mfma_i32_32x32x32_i8(a0, b1, acc[0][1], 0, 0, 0);
            acc[1][0] = __builtin_amdgcn_mfma_i32_32x32x32_i8(a1, b0, acc[1][0], 0, 0, 0);
            acc[1][1] = __builtin_amdgcn_mfma_i32_32x32x32_i8(a1, b1, acc[1][1], 0, 0, 0);
        }
    }

    // C/D layout (verified, dtype-independent): col = lane&31,
    // row = (reg&3) + 8*(reg>>2) + 4*(lane>>5)
    if (EPI == 1) {
#pragma unroll
        for (int fm = 0; fm < 2; ++fm) {
#pragma unroll
            for (int r = 0; r < 16; ++r) {
                int v  = acc[fm][0][r];
                int v2 = acc[fm][1][r];
                v = v > v2 ? v : v2;
#pragma unroll
                for (int m = 1; m <= 16; m <<= 1) {
                    int o = __shfl_xor(v, m, 64);
                    v = v > o ? v : o;
                }
                if ((lane & 31) == 0) {
                    int row = blockIdx.y * 128 + wr * 64 + fm * 32 + (r & 3) + 8 * (r >> 2) + 4 * (lane >> 5);
                    atomicMax(&rowmax[rowOff + row], v);
                }
            }
        }
#pragma unroll
        for (int fm = 0; fm < 2; ++fm)
#pragma unroll
            for (int r = 0; r < 16; ++r) {
                int row = blockIdx.y * 128 + wr * 64 + fm * 32 + (r & 3) + 8 * (r >> 2) + 4 * (lane >> 5);
                size_t base = (size_t)row * N + blockIdx.x * 128 + wc * 64 + (lane & 31);
                C[base]      = acc[fm][0][r];
                C[base + 32] = acc[fm][1][r];
            }
    } else {
#pragma unroll
        for (int fm = 0; fm < 2; ++fm)
#pragma unroll
            for (int r = 0; r < 16; ++r) {
                int row = blockIdx.y * 128 + wr * 64 + fm * 32 + (r & 3) + 8 * (r >> 2) + 4 * (lane >> 5);
                float s = os2[rowOff + row];
                size_t base = (size_t)(rowOff + row) * N + blockIdx.x * 128 + wc * 64 + (lane & 31);
                Out[base]      = (float)acc[fm][0][r] * s;
                Out[base + 32] = (float)acc[fm][1][r] * s;
            }
    }
}

// ---------------- host ---------------------------------------------------------
extern "C" void kernel_launch(void* const* d_in, const int* in_sizes, int n_in,
                              void* d_out, int out_size, void* d_ws, size_t ws_size,
                              hipStream_t stream) {
    const float* x  = (const float*)d_in[0];
    const float* W1 = (const float*)d_in[1];
    const float* W2 = (const float*)d_in[2];
    float* out = (float*)d_out;

    const int M = 8192, K1 = 4096, H = 16384, NOUT = 4096;
    const int NPART = 2048;

    uint8_t* ws = (uint8_t*)d_ws;
    size_t off = 0;
    auto alloc = [&](size_t bytes) -> void* {
        void* p = ws + off;
        off = (off + bytes + 255) & ~(size_t)255;
        return p;
    };
    char*   wq1  = (char*)alloc((size_t)H * K1);
    char*   wq2  = (char*)alloc((size_t)NOUT * H);
    char*   xq1  = (char*)alloc((size_t)M * K1);
    double* pd1  = (double*)alloc(NPART * 8);
    double* pd2  = (double*)alloc(NPART * 8);
    float*  scal = (float*)alloc(256);
    float*  xs1  = (float*)alloc(M * 4);
    float*  xs2  = (float*)alloc(M * 4);
    float*  os2  = (float*)alloc(M * 4);
    float*  g1s  = (float*)alloc(M * 4);
    int*    rm1  = (int*)alloc(M * 4);

    size_t remain = (ws_size > off) ? (ws_size - off) : 0;
    size_t perRow = (size_t)H * 4 + (size_t)H;   // C1 row + xq2 row
    long Rl = (long)(remain / perRow);
    int R = (int)((Rl / 128) * 128);
    if (R > M) R = M;
    if (R < 128) R = 128;                        // last-resort; needs ~170+10.5 MB ws
    int*  C1  = (int*)alloc((size_t)R * H * 4);
    char* xq2 = (char*)alloc((size_t)R * H);

    hipMemsetAsync(rm1, 0, M * 4, stream);
    k_abs_sum<<<NPART, 256, 0, stream>>>(W1, (long)H * K1 / 4, pd1);
    k_abs_sum<<<NPART, 256, 0, stream>>>(W2, (long)NOUT * H / 4, pd2);
    k_finalize<<<1, 256, 0, stream>>>(pd1, pd2, NPART, scal,
                                      1.0 / ((double)H * K1), 1.0 / ((double)NOUT * H));
    k_quant_w<<<4096, 256, 0, stream>>>(W1, wq1, (long)H * K1 / 4, scal, 0);
    k_quant_w<<<4096, 256, 0, stream>>>(W2, wq2, (long)NOUT * H / 4, scal, 1);
    k_quant_x<<<M, 256, 0, stream>>>(x, xq1, xs1, K1);

    for (int rowOff = 0; rowOff < M; rowOff += R) {
        int Mc = (M - rowOff < R) ? (M - rowOff) : R;
        dim3 grid1(H / 128, Mc / 128);
        k_gemm_i8<1><<<grid1, 256, 0, stream>>>(xq1 + (size_t)rowOff * K1, wq1, K1, H,
                                                C1, rm1, nullptr, nullptr, rowOff);
        k_rowscale2<<<(Mc + 255) / 256, 256, 0, stream>>>(rm1, xs1, scal, xs2, os2, g1s, rowOff, Mc);
        k_quant_h<<<2048, 256, 0, stream>>>(C1, xq2, xs2, g1s, rowOff, (long)Mc * H / 4);
        dim3 grid2(NOUT / 128, Mc / 128);
        k_gemm_i8<2><<<grid2, 256, 0, stream>>>(xq2, wq2, H, NOUT,
                                                nullptr, nullptr, out, os2, rowOff);
    }
}